// Round 12
// baseline (215.063 us; speedup 1.0000x reference)
//
#include <hip/hip_runtime.h>
#include <hip/hip_bf16.h>
#include <stdint.h>

typedef __bf16 bf16;
typedef bf16 bf16x8 __attribute__((ext_vector_type(8)));
typedef float f32x4 __attribute__((ext_vector_type(4)));
typedef float f32x16 __attribute__((ext_vector_type(16)));

// ---------------- tiny prep kernels ----------------

// s[b,c] = style[b,:] . style_w[c,:] + style_b[c]
__global__ void k_style(const float* __restrict__ style, const float* __restrict__ sw,
                        const float* __restrict__ sbias, float* __restrict__ s_out) {
    int gw = (blockIdx.x * blockDim.x + threadIdx.x) >> 6;
    int lane = threadIdx.x & 63;
    if (gw >= 512) return;
    int b = gw >> 7, c = gw & 127;
    const float* st = style + b * 512;
    const float* wr = sw + c * 512;
    float a = 0.f;
#pragma unroll
    for (int j = 0; j < 8; ++j) a += st[lane + 64 * j] * wr[lane + 64 * j];
    for (int off = 32; off > 0; off >>= 1) a += __shfl_down(a, off, 64);
    if (lane == 0) s_out[gw] = a + sbias[c];
}

// sig_inv[b,o] = rsqrt( sum_i (sum_tap W[o,i,tap]^2) * s[b,i]^2 + 1e-8 )
__global__ void k_sig(const float* __restrict__ weight, const float* __restrict__ s,
                      float* __restrict__ sig) {
    int gw = (blockIdx.x * blockDim.x + threadIdx.x) >> 6;
    int lane = threadIdx.x & 63;
    if (gw >= 512) return;
    int b = gw >> 7, o = gw & 127;
    float a = 0.f;
#pragma unroll
    for (int j = 0; j < 2; ++j) {
        int i = lane + 64 * j;
        const float* wr = weight + ((size_t)o * 128 + i) * 9;
        float wsq = 0.f;
#pragma unroll
        for (int t = 0; t < 9; ++t) wsq += wr[t] * wr[t];
        float sv = s[b * 128 + i];
        a += wsq * sv * sv;
    }
    for (int off = 32; off > 0; off >>= 1) a += __shfl_down(a, off, 64);
    if (lane == 0) sig[gw] = rsqrtf(a + 1e-8f);
}

// repack + style-fold: fp32 W[co][ci][9] * s[b][ci] ->
// bf16 wt[b4][chunk8][tap9][g2][co128][8ci]  (A-fragment order)
__global__ void k_wt(const float* __restrict__ weight, const float* __restrict__ s,
                     bf16* __restrict__ wt) {
    int i = blockIdx.x * 256 + threadIdx.x;
    if (i >= 589824) return;
    int j = i & 7;
    int co = (i >> 3) & 127;
    int g = (i >> 10) & 1;
    int tap = (i >> 11) % 9;
    int cb = (i >> 11) / 9;      // chunk + 8*b
    int chunk = cb & 7, b = cb >> 3;
    int ci = chunk * 16 + g * 8 + j;
    wt[i] = (bf16)(weight[((size_t)co * 128 + ci) * 9 + tap] * s[b * 128 + ci]);
}

// ---------------- main MFMA conv kernel ----------------
// grid 1024 (1-D, XCD-swizzled); block 256 = 4 waves; tile 128co x 256elem.
// r12: NO LDS, NO BARRIERS, NO waitcnt asm -- pure register dataflow.
// Rationale (r11): FETCH halved with zero speedup => not BW-bound; phase
// period 5250cyc vs ~2400cyc pipe content => barrier/wait serialization is
// the wall. MFMA B-fragment addresses are LINEAR in x (E = ha*1024 +
// (w0-1)*16 + el, lane-contiguous), wt is pre-packed in A-fragment order,
// so both operands load straight into VGPRs:
//   per (chunk,dh) phase: 9 deduped B-frags (frag(dw2,f)==frag(dw0,f+1);
//   el base: k<5 -> 32k, else 16+32(k-5)) = 72 coalesced dword loads + cvt,
//   6 A-frags = 6 dwordx4, 24 MFMA. Waves fully independent; compiler
//   pipelines across phases unimpeded.
// Cache model: phase X row 18KB -> L1 (32KB) catches the ~5x intra-block
// fragment overlap; wt[b] 288KB + cross-block h-halo -> XCD-local L2 (T1
// swizzle, r11-proven: FETCH at its 75MB floor).
__global__ __launch_bounds__(256, 2) void conv_main(
    const float* __restrict__ x, const bf16* __restrict__ wt,
    const float* __restrict__ sig_inv, const float* __restrict__ npar,
    const float* __restrict__ bpar, const float* __restrict__ noise,
    float* __restrict__ out) {
    const int tid = threadIdx.x;
    const int lane = tid & 63;
    const int l31 = lane & 31, lhi = lane >> 5;
    const int wm = (tid >> 6) & 1;     // co half (64co)
    const int wn = tid >> 7;           // el half (128el)

    // T1 swizzle: each XCD owns a contiguous (b, h-range) chunk
    const int hw = blockIdx.x;
    const int logical = (hw & 7) * 128 + (hw >> 3);
    const int w0 = (logical & 3) * 16;
    const int h = (logical >> 2) & 63;
    const int b = logical >> 8;

    const size_t bHW = (size_t)b * 65536;
    const bf16* wb = wt + (size_t)b * 147456;

    const bf16 zz = (bf16)0.f;
    const bf16x8 vz = {zz, zz, zz, zz, zz, zz, zz, zz};

    f32x16 acc[2][4] = {};

    // epilogue noise prefetch
    const size_t ebase = bHW + (size_t)h * 1024 + w0 * 16 + wn * 128;
    float ns[4];
#pragma unroll
    for (int nf = 0; nf < 4; ++nf) ns[nf] = noise[ebase + nf * 32 + l31];

    for (int c = 0; c < 8; ++c) {
        // this chunk's x base for this lane's ci-halfgroup (8 planes via j<<16)
        const float* xc = x + (((size_t)(b * 128 + c * 16 + lhi * 8)) << 16);
#pragma unroll
        for (int dh = 0; dh < 3; ++dh) {
            const int ha = h - 1 + dh;
            const bool okh = (unsigned)ha < 64u;
            const int Erow = ha * 1024 + (w0 - 1) * 16;

            // 9 unique B-frags of row (c,dh), direct from global fp32
            bf16x8 bf[9];
#pragma unroll
            for (int k = 0; k < 9; ++k) {
                const int eoff = (k < 5) ? 32 * k : 16 + 32 * (k - 5);
                const int e = wn * 128 + eoff + l31;
                const int wa = w0 - 1 + (e >> 4);
                const bool ok = okh & ((unsigned)wa < 64u);
                const int Ec = ok ? (Erow + e) : 0;   // clamp: always in-bounds
                bf16x8 v;
#pragma unroll
                for (int j = 0; j < 8; ++j)
                    v[j] = (bf16)xc[((size_t)j << 16) + Ec];
                bf[k] = ok ? v : vz;                  // halo -> exact zero
            }

            // 3 taps: A-frags direct from packed wt (L2-hot), 8 MFMA each.
            // B-frag index map: dw0 -> f, dw1 -> 5+f, dw2 -> 1+f.
#pragma unroll
            for (int dw = 0; dw < 3; ++dw) {
                const bf16* wg = wb +
                    ((size_t)((c * 9 + dh * 3 + dw) * 2 + lhi) * 128 + wm * 64 + l31) * 8;
                bf16x8 a0 = *(const bf16x8*)&wg[0];
                bf16x8 a1 = *(const bf16x8*)&wg[32 * 8];
                const int i0 = (dw == 0) ? 0 : (dw == 1) ? 5 : 1;
                acc[0][0] = __builtin_amdgcn_mfma_f32_32x32x16_bf16(a0, bf[i0 + 0], acc[0][0], 0, 0, 0);
                acc[0][1] = __builtin_amdgcn_mfma_f32_32x32x16_bf16(a0, bf[i0 + 1], acc[0][1], 0, 0, 0);
                acc[0][2] = __builtin_amdgcn_mfma_f32_32x32x16_bf16(a0, bf[i0 + 2], acc[0][2], 0, 0, 0);
                acc[0][3] = __builtin_amdgcn_mfma_f32_32x32x16_bf16(a0, bf[i0 + 3], acc[0][3], 0, 0, 0);
                acc[1][0] = __builtin_amdgcn_mfma_f32_32x32x16_bf16(a1, bf[i0 + 0], acc[1][0], 0, 0, 0);
                acc[1][1] = __builtin_amdgcn_mfma_f32_32x32x16_bf16(a1, bf[i0 + 1], acc[1][1], 0, 0, 0);
                acc[1][2] = __builtin_amdgcn_mfma_f32_32x32x16_bf16(a1, bf[i0 + 2], acc[1][2], 0, 0, 0);
                acc[1][3] = __builtin_amdgcn_mfma_f32_32x32x16_bf16(a1, bf[i0 + 3], acc[1][3], 0, 0, 0);
            }
        }
    }

    // epilogue: D col = lane&31 (elem), row = (reg&3)+8*(reg>>2)+4*lhi (co)
#pragma unroll
    for (int fm = 0; fm < 2; ++fm) {
        int cob = wm * 64 + fm * 32 + 4 * lhi;
#pragma unroll
        for (int q = 0; q < 4; ++q) {
            int co4 = cob + 8 * q;
            f32x4 sg = *(const f32x4*)&sig_inv[b * 128 + co4];
            f32x4 np4 = *(const f32x4*)&npar[co4];
            f32x4 bp4 = *(const f32x4*)&bpar[co4];
#pragma unroll
            for (int r = 0; r < 4; ++r) {
                int co = co4 + r;
                float* orow = out + ((size_t)(b * 128 + co) * 64 + h) * 1024 +
                              w0 * 16 + wn * 128;
#pragma unroll
                for (int nf = 0; nf < 4; ++nf) {
                    float v = acc[fm][nf][q * 4 + r];
                    orow[nf * 32 + l31] = v * sg[r] + np4[r] * ns[nf] + bp4[r];
                }
            }
        }
    }
}

// ---------------- fp32 fallback (ws too small) ----------------
__global__ void k_naive(const float* __restrict__ x, const float* __restrict__ weight,
                        const float* __restrict__ s, const float* __restrict__ sig,
                        const float* __restrict__ npar, const float* __restrict__ bpar,
                        const float* __restrict__ noise, float* __restrict__ out) {
    size_t o = (size_t)blockIdx.x * 256 + threadIdx.x;
    int t = o & 15, w = (o >> 4) & 63, h = (o >> 10) & 63;
    int co = (o >> 16) & 127, b = (int)(o >> 23);
    float a = 0.f;
    for (int ci = 0; ci < 128; ++ci) {
        const float* xr = x + (size_t)(b * 128 + ci) * 65536;
        const float* wr = weight + ((size_t)co * 128 + ci) * 9;
        float p = 0.f;
#pragma unroll
        for (int kh = 0; kh < 3; ++kh) {
            int ha = h + kh - 1;
            if ((unsigned)ha >= 64u) continue;
#pragma unroll
            for (int kw = 0; kw < 3; ++kw) {
                int wa = w + kw - 1;
                if ((unsigned)wa >= 64u) continue;
                p += xr[(ha * 64 + wa) * 16 + t] * wr[kh * 3 + kw];
            }
        }
        a += p * s[b * 128 + ci];
    }
    int E = b * 65536 + (h * 64 + w) * 16 + t;
    out[o] = a * sig[b * 128 + co] + npar[co] * noise[E] + bpar[co];
}

// ---------------- host ----------------
extern "C" void kernel_launch(void* const* d_in, const int* in_sizes, int n_in,
                              void* d_out, int out_size, void* d_ws, size_t ws_size,
                              hipStream_t stream) {
    const float* x      = (const float*)d_in[0];
    const float* style  = (const float*)d_in[1];
    const float* noise  = (const float*)d_in[2];
    const float* weight = (const float*)d_in[3];
    const float* sw     = (const float*)d_in[4];
    const float* sb     = (const float*)d_in[5];
    const float* npar   = (const float*)d_in[6];
    const float* bpar   = (const float*)d_in[7];
    float* out = (float*)d_out;

    float* s_buf   = (float*)d_ws;                         // 512 f32
    float* sig_buf = s_buf + 512;                          // 512 f32
    bf16*  wt      = (bf16*)((char*)d_ws + 8192);          // 4 x 294912 B
    const size_t NEED = 8192 + 4 * 294912ull;

    k_style<<<dim3(128), dim3(256), 0, stream>>>(style, sw, sb, s_buf);
    k_sig<<<dim3(128), dim3(256), 0, stream>>>(weight, s_buf, sig_buf);
    if (ws_size >= NEED) {
        k_wt<<<dim3(2304), dim3(256), 0, stream>>>(weight, s_buf, wt);
        conv_main<<<dim3(1024), dim3(256), 0, stream>>>(
            x, wt, sig_buf, npar, bpar, noise, out);
    } else {
        k_naive<<<dim3(131072), dim3(256), 0, stream>>>(
            x, weight, s_buf, sig_buf, npar, bpar, noise, out);
    }
}

// Round 13
// 157.822 us; speedup vs baseline: 1.3627x; 1.3627x over previous
//
#include <hip/hip_runtime.h>
#include <hip/hip_bf16.h>
#include <stdint.h>

typedef __bf16 bf16;
typedef bf16 bf16x8 __attribute__((ext_vector_type(8)));
typedef float f32x4 __attribute__((ext_vector_type(4)));
typedef float f32x16 __attribute__((ext_vector_type(16)));

// ---------------- tiny prep kernels ----------------

// s[b,c] = style[b,:] . style_w[c,:] + style_b[c]
__global__ void k_style(const float* __restrict__ style, const float* __restrict__ sw,
                        const float* __restrict__ sbias, float* __restrict__ s_out) {
    int gw = (blockIdx.x * blockDim.x + threadIdx.x) >> 6;
    int lane = threadIdx.x & 63;
    if (gw >= 512) return;
    int b = gw >> 7, c = gw & 127;
    const float* st = style + b * 512;
    const float* wr = sw + c * 512;
    float a = 0.f;
#pragma unroll
    for (int j = 0; j < 8; ++j) a += st[lane + 64 * j] * wr[lane + 64 * j];
    for (int off = 32; off > 0; off >>= 1) a += __shfl_down(a, off, 64);
    if (lane == 0) s_out[gw] = a + sbias[c];
}

// sig_inv[b,o] = rsqrt( sum_i (sum_tap W[o,i,tap]^2) * s[b,i]^2 + 1e-8 )
__global__ void k_sig(const float* __restrict__ weight, const float* __restrict__ s,
                      float* __restrict__ sig) {
    int gw = (blockIdx.x * blockDim.x + threadIdx.x) >> 6;
    int lane = threadIdx.x & 63;
    if (gw >= 512) return;
    int b = gw >> 7, o = gw & 127;
    float a = 0.f;
#pragma unroll
    for (int j = 0; j < 2; ++j) {
        int i = lane + 64 * j;
        const float* wr = weight + ((size_t)o * 128 + i) * 9;
        float wsq = 0.f;
#pragma unroll
        for (int t = 0; t < 9; ++t) wsq += wr[t] * wr[t];
        float sv = s[b * 128 + i];
        a += wsq * sv * sv;
    }
    for (int off = 32; off > 0; off >>= 1) a += __shfl_down(a, off, 64);
    if (lane == 0) sig[gw] = rsqrtf(a + 1e-8f);
}

// repack weight fp32 [co][ci][9] -> bf16 wt[chunk8][tap9][g2][co128][8ci]
// (A-fragment order; NOT style-scaled -- the scale lives in xt)
__global__ void k_wt(const float* __restrict__ weight, bf16* __restrict__ wt) {
    int i = blockIdx.x * 256 + threadIdx.x;
    if (i >= 147456) return;
    int j = i & 7;
    int co = (i >> 3) & 127;
    int g = (i >> 10) & 1;
    int tap = (i >> 11) % 9;
    int chunk = (i >> 11) / 9;
    int ci = chunk * 16 + g * 8 + j;
    wt[i] = (bf16)weight[((size_t)co * 128 + ci) * 9 + tap];
}

// x fp32 [b][ci][hwt] * s[b][ci] -> bf16 xt[b][g=ci>>3][e=hwt][8ci]
// The [e][8ci] inner layout makes an MFMA B-fragment = one contiguous
// 16B-per-lane dwordx4 load (lane = element index).
__global__ void k_xt(const float* __restrict__ x, const float* __restrict__ s,
                     bf16* __restrict__ xt) {
    int E = blockIdx.x * 256 + threadIdx.x;   // 0..262143
    int b = E >> 16, e = E & 65535;
    const float* xb = x + (size_t)b * 8388608 + e;
    const float* sb = s + b * 128;
#pragma unroll 4
    for (int g = 0; g < 16; ++g) {
        bf16x8 v;
#pragma unroll
        for (int j = 0; j < 8; ++j)
            v[j] = (bf16)(xb[(size_t)(g * 8 + j) * 65536] * sb[g * 8 + j]);
        *(bf16x8*)(xt + ((((size_t)b * 16 + g) << 16) + e) * 8) = v;
    }
}

// ---------------- main MFMA conv kernel ----------------
// grid 1024 (1-D, XCD-swizzled); block 256 = 4 waves; tile 128co x 256elem.
// r13: pure register dataflow -- NO LDS, NO barriers, NO waitcnt asm.
// r12's failure was operand format (8 plane-strided fp32 scalar loads + cvt
// per B-frag); with bf16 xt restored, a B-frag is ONE coalesced dwordx4.
// Per (chunk,dh) phase per wave: 9 B-frag loads (deduped across dw:
// frag(dw,f) -> bf[{0,5,1}[dw] + f]) + 6 A-frag loads (packed wt, L2-hot)
// + 24 MFMA. ~15 VMEM/phase vs r12's ~130. Waves fully independent; the
// compiler pipelines loads across phases with nothing blocking code motion.
// Cache model (r12-verified: FETCH stayed at its 75MB floor even with
// per-wave redundancy): wm-pair redundancy -> L1; halo + wt -> XCD-local L2
// (T1 swizzle, r11-proven).
__global__ __launch_bounds__(256, 2) void conv_main(
    const bf16* __restrict__ xt, const bf16* __restrict__ wt,
    const float* __restrict__ sig_inv, const float* __restrict__ npar,
    const float* __restrict__ bpar, const float* __restrict__ noise,
    float* __restrict__ out) {
    const int tid = threadIdx.x;
    const int lane = tid & 63;
    const int l31 = lane & 31, lhi = lane >> 5;
    const int wm = (tid >> 6) & 1;     // co half (64co)
    const int wn = tid >> 7;           // el half (128el)

    // T1 swizzle: each XCD owns a contiguous (b, h-range) chunk
    const int hw = blockIdx.x;
    const int logical = (hw & 7) * 128 + (hw >> 3);
    const int w0 = (logical & 3) * 16;
    const int h = (logical >> 2) & 63;
    const int b = logical >> 8;

    const size_t bHW = (size_t)b * 65536;

    // per-k fragment element offsets + w-validity (constant across c,dh)
    int Eoff[9];
    bool okw[9];
#pragma unroll
    for (int k = 0; k < 9; ++k) {
        const int eoff = (k < 5) ? 32 * k : 16 + 32 * (k - 5);
        const int e = wn * 128 + eoff + l31;
        const int wa = w0 - 1 + (e >> 4);
        okw[k] = (unsigned)wa < 64u;
        Eoff[k] = (w0 - 1) * 16 + e;   // >= 0 whenever okw[k]
    }

    const bf16 zz = (bf16)0.f;
    const bf16x8 vz = {zz, zz, zz, zz, zz, zz, zz, zz};

    f32x16 acc[2][4] = {};

    // epilogue noise prefetch
    const size_t ebase = bHW + (size_t)h * 1024 + w0 * 16 + wn * 128;
    float ns[4];
#pragma unroll
    for (int nf = 0; nf < 4; ++nf) ns[nf] = noise[ebase + nf * 32 + l31];

    for (int c = 0; c < 8; ++c) {
        // lane's K-halfgroup plane of xt for this chunk (g = c*2 + lhi)
        const bf16* xcl = xt + (((size_t)(b * 16 + c * 2 + lhi)) << 16) * 8;
#pragma unroll
        for (int dh = 0; dh < 3; ++dh) {
            const int ha = h - 1 + dh;
            const bool okh = (unsigned)ha < 64u;
            const int Ebase = ha * 1024;

            // 9 unique B-frags of row (c,dh): one dwordx4 each
            bf16x8 bf[9];
#pragma unroll
            for (int k = 0; k < 9; ++k) {
                const bool ok = okh & okw[k];
                const int E = ok ? (Ebase + Eoff[k]) : 0;   // clamp in-bounds
                bf16x8 v = *(const bf16x8*)(xcl + (size_t)E * 8);
                bf[k] = ok ? v : vz;                        // halo -> zero
            }

            // 3 taps; B-frag map: dw0 -> f, dw1 -> 5+f, dw2 -> 1+f
#pragma unroll
            for (int dw = 0; dw < 3; ++dw) {
                const bf16* wg = wt +
                    ((size_t)((c * 9 + dh * 3 + dw) * 2 + lhi) * 128 + wm * 64 + l31) * 8;
                bf16x8 a0 = *(const bf16x8*)&wg[0];
                bf16x8 a1 = *(const bf16x8*)&wg[32 * 8];
                const int i0 = (dw == 0) ? 0 : (dw == 1) ? 5 : 1;
                acc[0][0] = __builtin_amdgcn_mfma_f32_32x32x16_bf16(a0, bf[i0 + 0], acc[0][0], 0, 0, 0);
                acc[0][1] = __builtin_amdgcn_mfma_f32_32x32x16_bf16(a0, bf[i0 + 1], acc[0][1], 0, 0, 0);
                acc[0][2] = __builtin_amdgcn_mfma_f32_32x32x16_bf16(a0, bf[i0 + 2], acc[0][2], 0, 0, 0);
                acc[0][3] = __builtin_amdgcn_mfma_f32_32x32x16_bf16(a0, bf[i0 + 3], acc[0][3], 0, 0, 0);
                acc[1][0] = __builtin_amdgcn_mfma_f32_32x32x16_bf16(a1, bf[i0 + 0], acc[1][0], 0, 0, 0);
                acc[1][1] = __builtin_amdgcn_mfma_f32_32x32x16_bf16(a1, bf[i0 + 1], acc[1][1], 0, 0, 0);
                acc[1][2] = __builtin_amdgcn_mfma_f32_32x32x16_bf16(a1, bf[i0 + 2], acc[1][2], 0, 0, 0);
                acc[1][3] = __builtin_amdgcn_mfma_f32_32x32x16_bf16(a1, bf[i0 + 3], acc[1][3], 0, 0, 0);
            }
        }
    }

    // epilogue: D col = lane&31 (elem), row = (reg&3)+8*(reg>>2)+4*lhi (co)
#pragma unroll
    for (int fm = 0; fm < 2; ++fm) {
        int cob = wm * 64 + fm * 32 + 4 * lhi;
#pragma unroll
        for (int q = 0; q < 4; ++q) {
            int co4 = cob + 8 * q;
            f32x4 sg = *(const f32x4*)&sig_inv[b * 128 + co4];
            f32x4 np4 = *(const f32x4*)&npar[co4];
            f32x4 bp4 = *(const f32x4*)&bpar[co4];
#pragma unroll
            for (int r = 0; r < 4; ++r) {
                int co = co4 + r;
                float* orow = out + ((size_t)(b * 128 + co) * 64 + h) * 1024 +
                              w0 * 16 + wn * 128;
#pragma unroll
                for (int nf = 0; nf < 4; ++nf) {
                    float v = acc[fm][nf][q * 4 + r];
                    orow[nf * 32 + l31] = v * sg[r] + np4[r] * ns[nf] + bp4[r];
                }
            }
        }
    }
}

// ---------------- fp32 fallback (ws too small) ----------------
__global__ void k_naive(const float* __restrict__ x, const float* __restrict__ weight,
                        const float* __restrict__ s, const float* __restrict__ sig,
                        const float* __restrict__ npar, const float* __restrict__ bpar,
                        const float* __restrict__ noise, float* __restrict__ out) {
    size_t o = (size_t)blockIdx.x * 256 + threadIdx.x;
    int t = o & 15, w = (o >> 4) & 63, h = (o >> 10) & 63;
    int co = (o >> 16) & 127, b = (int)(o >> 23);
    float a = 0.f;
    for (int ci = 0; ci < 128; ++ci) {
        const float* xr = x + (size_t)(b * 128 + ci) * 65536;
        const float* wr = weight + ((size_t)co * 128 + ci) * 9;
        float p = 0.f;
#pragma unroll
        for (int kh = 0; kh < 3; ++kh) {
            int ha = h + kh - 1;
            if ((unsigned)ha >= 64u) continue;
#pragma unroll
            for (int kw = 0; kw < 3; ++kw) {
                int wa = w + kw - 1;
                if ((unsigned)wa >= 64u) continue;
                p += xr[(ha * 64 + wa) * 16 + t] * wr[kh * 3 + kw];
            }
        }
        a += p * s[b * 128 + ci];
    }
    int E = b * 65536 + (h * 64 + w) * 16 + t;
    out[o] = a * sig[b * 128 + co] + npar[co] * noise[E] + bpar[co];
}

// ---------------- host ----------------
extern "C" void kernel_launch(void* const* d_in, const int* in_sizes, int n_in,
                              void* d_out, int out_size, void* d_ws, size_t ws_size,
                              hipStream_t stream) {
    const float* x      = (const float*)d_in[0];
    const float* style  = (const float*)d_in[1];
    const float* noise  = (const float*)d_in[2];
    const float* weight = (const float*)d_in[3];
    const float* sw     = (const float*)d_in[4];
    const float* sb     = (const float*)d_in[5];
    const float* npar   = (const float*)d_in[6];
    const float* bpar   = (const float*)d_in[7];
    float* out = (float*)d_out;

    float* s_buf   = (float*)d_ws;                         // 512 f32
    float* sig_buf = s_buf + 512;                          // 512 f32
    bf16*  wt      = (bf16*)((char*)d_ws + 8192);          // 294912 B
    bf16*  xt      = (bf16*)((char*)d_ws + 8192 + 294912); // 67108864 B
    const size_t NEED = 8192 + 294912 + 67108864ull;

    k_style<<<dim3(128), dim3(256), 0, stream>>>(style, sw, sb, s_buf);
    k_sig<<<dim3(128), dim3(256), 0, stream>>>(weight, s_buf, sig_buf);
    if (ws_size >= NEED) {
        k_wt<<<dim3(576), dim3(256), 0, stream>>>(weight, wt);
        k_xt<<<dim3(1024), dim3(256), 0, stream>>>(x, s_buf, xt);
        conv_main<<<dim3(1024), dim3(256), 0, stream>>>(
            xt, wt, sig_buf, npar, bpar, noise, out);
    } else {
        k_naive<<<dim3(131072), dim3(256), 0, stream>>>(
            x, weight, s_buf, sig_buf, npar, bpar, noise, out);
    }
}

// Round 14
// 112.115 us; speedup vs baseline: 1.9182x; 1.4077x over previous
//
#include <hip/hip_runtime.h>
#include <hip/hip_bf16.h>
#include <stdint.h>

typedef __bf16 bf16;
typedef bf16 bf16x8 __attribute__((ext_vector_type(8)));
typedef float f32x4 __attribute__((ext_vector_type(4)));
typedef float f32x16 __attribute__((ext_vector_type(16)));

#define AS1 __attribute__((address_space(1)))

// ---------------- tiny prep kernels ----------------

// s[b,c] = style[b,:] . style_w[c,:] + style_b[c]
__global__ void k_style(const float* __restrict__ style, const float* __restrict__ sw,
                        const float* __restrict__ sbias, float* __restrict__ s_out) {
    int gw = (blockIdx.x * blockDim.x + threadIdx.x) >> 6;
    int lane = threadIdx.x & 63;
    if (gw >= 512) return;
    int b = gw >> 7, c = gw & 127;
    const float* st = style + b * 512;
    const float* wr = sw + c * 512;
    float a = 0.f;
#pragma unroll
    for (int j = 0; j < 8; ++j) a += st[lane + 64 * j] * wr[lane + 64 * j];
    for (int off = 32; off > 0; off >>= 1) a += __shfl_down(a, off, 64);
    if (lane == 0) s_out[gw] = a + sbias[c];
}

// sig_inv[b,o] = rsqrt( sum_i (sum_tap W[o,i,tap]^2) * s[b,i]^2 + 1e-8 )
__global__ void k_sig(const float* __restrict__ weight, const float* __restrict__ s,
                      float* __restrict__ sig) {
    int gw = (blockIdx.x * blockDim.x + threadIdx.x) >> 6;
    int lane = threadIdx.x & 63;
    if (gw >= 512) return;
    int b = gw >> 7, o = gw & 127;
    float a = 0.f;
#pragma unroll
    for (int j = 0; j < 2; ++j) {
        int i = lane + 64 * j;
        const float* wr = weight + ((size_t)o * 128 + i) * 9;
        float wsq = 0.f;
#pragma unroll
        for (int t = 0; t < 9; ++t) wsq += wr[t] * wr[t];
        float sv = s[b * 128 + i];
        a += wsq * sv * sv;
    }
    for (int off = 32; off > 0; off >>= 1) a += __shfl_down(a, off, 64);
    if (lane == 0) sig[gw] = rsqrtf(a + 1e-8f);
}

// repack + style-fold: fp32 W[co][ci][9] * s[b][ci] ->
// bf16 wt[b4][chunk8][tap9][g2][co128][8ci]  (A-fragment order)
__global__ void k_wt(const float* __restrict__ weight, const float* __restrict__ s,
                     bf16* __restrict__ wt) {
    int i = blockIdx.x * 256 + threadIdx.x;
    if (i >= 589824) return;
    int j = i & 7;
    int co = (i >> 3) & 127;
    int g = (i >> 10) & 1;
    int tap = (i >> 11) % 9;
    int cb = (i >> 11) / 9;      // chunk + 8*b
    int chunk = cb & 7, b = cb >> 3;
    int ci = chunk * 16 + g * 8 + j;
    wt[i] = (bf16)(weight[((size_t)co * 128 + ci) * 9 + tap] * s[b * 128 + ci]);
}

// ---------------- main MFMA conv kernel ----------------
// grid 1024 (1-D, XCD-swizzled); block 256 = 4 waves; tile 128co x 256elem.
// r14: the r11 kernel is LDS-READ-BW-BOUND (audit: 18 ds_read_b128/wave-phase
// x 16 waves x 24 phases x 4 blk/CU = 27.6MB / 112 B/cyc/CU = 246 kcyc =
// the observed ~100us; conflicts=0, all other pipes <=30%, every sync/occ
// restructure null because none changed LDS bytes). Fix: A-frags (one
// dwordx4 each from packed per-batch wt, 288KB = XCD-local L2-hot via T1)
// bypass LDS entirely -- plain global loads issued BEFORE xload(p+1) so the
// in-order vmcnt wait for A does not drain the X prefetch (r4 lesson).
// The W ring, its DMAs and all manual vmcnt bookkeeping are deleted.
// LDS = X ring only (3 x 9216B); reads/wave-phase 18 -> 12 (-33% on the
// saturated pipe).
// Per phase p (row = (chunk,dh) = p/3, p%3):
//   1. xstore(p):  cvt XL(p) -> bf16x8 -> 3 ds_write_b128 (X slot p%3)
//   2. aload(p):   6 global dwordx4 A-frags for this phase (oldest VMEM)
//   3. xload(p+1): 24 fp32 global loads into XL regs (youngest)
//   4. lgkmcnt(0) flush ds_writes ; s_barrier
//   5. compute(p): 12 ds_read_b128 (B) + 24 MFMA (A from regs)
// Ring safety: 3 slots, write at p overwrites row p-3; barrier(p-1)
// collectively retires compute(p-2) and earlier readers. SAFE (as r8-r11).
// LDS: 27648 B -> 2 blocks/CU.
__global__ __launch_bounds__(256, 2) void conv_main(
    const float* __restrict__ x, const bf16* __restrict__ wt,
    const float* __restrict__ sig_inv, const float* __restrict__ npar,
    const float* __restrict__ bpar, const float* __restrict__ noise,
    float* __restrict__ out) {
    __shared__ bf16 Xr[3][576 * 8];    // 3 x 9216 B  X row ring [g2][e288][8ci]

    const int tid = threadIdx.x;
    const int lane = tid & 63;
    const int l31 = lane & 31, lhi = lane >> 5;
    const int wm = (tid >> 6) & 1;     // co half (64co)
    const int wn = tid >> 7;           // el half (128el)

    // T1 swizzle: each XCD owns a contiguous (b, h-range) chunk
    const int hw = blockIdx.x;
    const int logical = (hw & 7) * 128 + (hw >> 3);
    const int w0 = (logical & 3) * 16;
    const int h = (logical >> 2) & 63;
    const int b = logical >> 8;

    const size_t bHW = (size_t)b * 65536;
    const bf16* wb = wt + (size_t)b * 147456;

    float XL[24];                      // in-flight X row (3 cells x 8 ci)
    bf16x8 af[6];                      // this phase's A-frags (from global)

    // issue 24 fp32 loads for row g (3 cells/thread, wrap-dup past 576).
    auto xload = [&](int g) {
        int cg = g / 3, dhg = g - cg * 3;
        int ha = h - 1 + dhg;
#pragma unroll
        for (int cc = 0; cc < 3; ++cc) {
            int v0 = cc * 256 + tid;
            int v = v0 >= 576 ? v0 - 576 : v0;
            int gg = v / 288, e = v - gg * 288;
            int wa = w0 - 1 + (e >> 4);
            bool ok = ((unsigned)ha < 64u) & ((unsigned)wa < 64u);
            int E = (ha * 64 + wa) * 16 + (e & 15);
            int Ec = ok ? E : 0;       // clamp: loads always in-bounds
            const AS1 float* xp = (const AS1 float*)x +
                (((size_t)(b * 128 + cg * 16 + gg * 8)) << 16) + Ec;
#pragma unroll
            for (int j = 0; j < 8; ++j) XL[cc * 8 + j] = xp[(size_t)j << 16];
        }
    };

    // cvt + ds_write row g from XL (halo rows/cols zeroed by value-select).
    auto xstore = [&](int g) {
        int dhg = g % 3;
        int ha = h - 1 + dhg;
        const bf16 zz = (bf16)0.f;
        const bf16x8 vz = {zz, zz, zz, zz, zz, zz, zz, zz};
#pragma unroll
        for (int cc = 0; cc < 3; ++cc) {
            int v0 = cc * 256 + tid;
            int v = v0 >= 576 ? v0 - 576 : v0;
            int gg = v / 288, e = v - gg * 288;
            int wa = w0 - 1 + (e >> 4);
            bool ok = ((unsigned)ha < 64u) & ((unsigned)wa < 64u);
            bf16x8 vv;
#pragma unroll
            for (int j = 0; j < 8; ++j) vv[j] = (bf16)XL[cc * 8 + j];
            vv = ok ? vv : vz;
            *(bf16x8*)&Xr[dhg][v * 8] = vv;
        }
    };

    // 6 A-frag loads for phase (c,dh): L1/L2-hit dwordx4, lane-contiguous.
    auto aload = [&](int c, int dh) {
#pragma unroll
        for (int dw = 0; dw < 3; ++dw) {
            const bf16* wg = wb +
                ((size_t)((c * 9 + dh * 3 + dw) * 2 + lhi) * 128 + wm * 64 + l31) * 8;
            af[dw * 2 + 0] = *(const bf16x8*)&wg[0];
            af[dw * 2 + 1] = *(const bf16x8*)&wg[32 * 8];
        }
    };

    f32x16 acc[2][4] = {};

    // epilogue noise first (oldest VMEM, retired at the first xstore wait)
    const size_t ebase = bHW + (size_t)h * 1024 + w0 * 16 + wn * 128;
    float ns[4];
#pragma unroll
    for (int nf = 0; nf < 4; ++nf) ns[nf] = noise[ebase + nf * 32 + l31];
    __builtin_amdgcn_sched_barrier(0);

    // prologue: XL <- row 0
    xload(0);
    __builtin_amdgcn_sched_barrier(0);

#define PHASE(c, dh, DONEXT)                                                   \
    {                                                                          \
        xstore(3 * (c) + (dh));       /* implicit wait retires XL(p) */        \
        __builtin_amdgcn_sched_barrier(0);                                     \
        aload((c), (dh));             /* A older than xload(p+1) */            \
        __builtin_amdgcn_sched_barrier(0);                                     \
        if (DONEXT) xload(3 * (c) + (dh) + 1);                                 \
        __builtin_amdgcn_sched_barrier(0);                                     \
        asm volatile("s_waitcnt lgkmcnt(0)" ::: "memory");                     \
        __builtin_amdgcn_s_barrier();                                          \
        _Pragma("unroll")                                                      \
        for (int dw = 0; dw < 3; ++dw) {                                       \
            bf16x8 a0 = af[dw * 2 + 0];                                        \
            bf16x8 a1 = af[dw * 2 + 1];                                        \
            const bf16* xb =                                                   \
                &Xr[dh][(lhi * 288 + dw * 16 + wn * 128 + l31) * 8];           \
            bf16x8 b0 = *(const bf16x8*)&xb[0];                                \
            bf16x8 b1 = *(const bf16x8*)&xb[32 * 8];                           \
            bf16x8 b2 = *(const bf16x8*)&xb[64 * 8];                           \
            bf16x8 b3 = *(const bf16x8*)&xb[96 * 8];                           \
            acc[0][0] = __builtin_amdgcn_mfma_f32_32x32x16_bf16(a0, b0, acc[0][0], 0, 0, 0); \
            acc[0][1] = __builtin_amdgcn_mfma_f32_32x32x16_bf16(a0, b1, acc[0][1], 0, 0, 0); \
            acc[0][2] = __builtin_amdgcn_mfma_f32_32x32x16_bf16(a0, b2, acc[0][2], 0, 0, 0); \
            acc[0][3] = __builtin_amdgcn_mfma_f32_32x32x16_bf16(a0, b3, acc[0][3], 0, 0, 0); \
            acc[1][0] = __builtin_amdgcn_mfma_f32_32x32x16_bf16(a1, b0, acc[1][0], 0, 0, 0); \
            acc[1][1] = __builtin_amdgcn_mfma_f32_32x32x16_bf16(a1, b1, acc[1][1], 0, 0, 0); \
            acc[1][2] = __builtin_amdgcn_mfma_f32_32x32x16_bf16(a1, b2, acc[1][2], 0, 0, 0); \
            acc[1][3] = __builtin_amdgcn_mfma_f32_32x32x16_bf16(a1, b3, acc[1][3], 0, 0, 0); \
        }                                                                      \
    }

    for (int c = 0; c < 7; ++c) {
        PHASE(c, 0, true);
        PHASE(c, 1, true);
        PHASE(c, 2, true);
    }
    PHASE(7, 0, true);
    PHASE(7, 1, true);
    PHASE(7, 2, false);
#undef PHASE

    // epilogue: D col = lane&31 (elem), row = (reg&3)+8*(reg>>2)+4*lhi (co)
#pragma unroll
    for (int fm = 0; fm < 2; ++fm) {
        int cob = wm * 64 + fm * 32 + 4 * lhi;
#pragma unroll
        for (int q = 0; q < 4; ++q) {
            int co4 = cob + 8 * q;
            f32x4 sg = *(const f32x4*)&sig_inv[b * 128 + co4];
            f32x4 np4 = *(const f32x4*)&npar[co4];
            f32x4 bp4 = *(const f32x4*)&bpar[co4];
#pragma unroll
            for (int r = 0; r < 4; ++r) {
                int co = co4 + r;
                float* orow = out + ((size_t)(b * 128 + co) * 64 + h) * 1024 +
                              w0 * 16 + wn * 128;
#pragma unroll
                for (int nf = 0; nf < 4; ++nf) {
                    float v = acc[fm][nf][q * 4 + r];
                    orow[nf * 32 + l31] = v * sg[r] + np4[r] * ns[nf] + bp4[r];
                }
            }
        }
    }
}

// ---------------- fp32 fallback (ws too small) ----------------
__global__ void k_naive(const float* __restrict__ x, const float* __restrict__ weight,
                        const float* __restrict__ s, const float* __restrict__ sig,
                        const float* __restrict__ npar, const float* __restrict__ bpar,
                        const float* __restrict__ noise, float* __restrict__ out) {
    size_t o = (size_t)blockIdx.x * 256 + threadIdx.x;
    int t = o & 15, w = (o >> 4) & 63, h = (o >> 10) & 63;
    int co = (o >> 16) & 127, b = (int)(o >> 23);
    float a = 0.f;
    for (int ci = 0; ci < 128; ++ci) {
        const float* xr = x + (size_t)(b * 128 + ci) * 65536;
        const float* wr = weight + ((size_t)co * 128 + ci) * 9;
        float p = 0.f;
#pragma unroll
        for (int kh = 0; kh < 3; ++kh) {
            int ha = h + kh - 1;
            if ((unsigned)ha >= 64u) continue;
#pragma unroll
            for (int kw = 0; kw < 3; ++kw) {
                int wa = w + kw - 1;
                if ((unsigned)wa >= 64u) continue;
                p += xr[(ha * 64 + wa) * 16 + t] * wr[kh * 3 + kw];
            }
        }
        a += p * s[b * 128 + ci];
    }
    int E = b * 65536 + (h * 64 + w) * 16 + t;
    out[o] = a * sig[b * 128 + co] + npar[co] * noise[E] + bpar[co];
}

// ---------------- host ----------------
extern "C" void kernel_launch(void* const* d_in, const int* in_sizes, int n_in,
                              void* d_out, int out_size, void* d_ws, size_t ws_size,
                              hipStream_t stream) {
    const float* x      = (const float*)d_in[0];
    const float* style  = (const float*)d_in[1];
    const float* noise  = (const float*)d_in[2];
    const float* weight = (const float*)d_in[3];
    const float* sw     = (const float*)d_in[4];
    const float* sb     = (const float*)d_in[5];
    const float* npar   = (const float*)d_in[6];
    const float* bpar   = (const float*)d_in[7];
    float* out = (float*)d_out;

    float* s_buf   = (float*)d_ws;                         // 512 f32
    float* sig_buf = s_buf + 512;                          // 512 f32
    bf16*  wt      = (bf16*)((char*)d_ws + 8192);          // 4 x 294912 B
    const size_t NEED = 8192 + 4 * 294912ull;

    k_style<<<dim3(128), dim3(256), 0, stream>>>(style, sw, sb, s_buf);
    k_sig<<<dim3(128), dim3(256), 0, stream>>>(weight, s_buf, sig_buf);
    if (ws_size >= NEED) {
        k_wt<<<dim3(2304), dim3(256), 0, stream>>>(weight, s_buf, wt);
        conv_main<<<dim3(1024), dim3(256), 0, stream>>>(
            x, wt, sig_buf, npar, bpar, noise, out);
    } else {
        k_naive<<<dim3(131072), dim3(256), 0, stream>>>(
            x, weight, s_buf, sig_buf, npar, bpar, noise, out);
    }
}

// Round 15
// 109.769 us; speedup vs baseline: 1.9592x; 1.0214x over previous
//
#include <hip/hip_runtime.h>
#include <hip/hip_bf16.h>
#include <stdint.h>

typedef __bf16 bf16;
typedef bf16 bf16x8 __attribute__((ext_vector_type(8)));
typedef float f32x4 __attribute__((ext_vector_type(4)));
typedef float f32x16 __attribute__((ext_vector_type(16)));

#define AS1 __attribute__((address_space(1)))
#define AS3 __attribute__((address_space(3)))

__device__ __forceinline__ void async_copy16(const void* g, void* l) {
    __builtin_amdgcn_global_load_lds((const AS1 uint32_t*)(g),
                                     (AS3 uint32_t*)(l), 16, 0, 0);
}

template <int N> __device__ __forceinline__ void waitv();
template <> __device__ __forceinline__ void waitv<0>()  { asm volatile("s_waitcnt vmcnt(0)"  ::: "memory"); }
template <> __device__ __forceinline__ void waitv<27>() { asm volatile("s_waitcnt vmcnt(27)" ::: "memory"); }

// ---------------- tiny prep kernels ----------------

// s[b,c] = style[b,:] . style_w[c,:] + style_b[c]
__global__ void k_style(const float* __restrict__ style, const float* __restrict__ sw,
                        const float* __restrict__ sbias, float* __restrict__ s_out) {
    int gw = (blockIdx.x * blockDim.x + threadIdx.x) >> 6;
    int lane = threadIdx.x & 63;
    if (gw >= 512) return;
    int b = gw >> 7, c = gw & 127;
    const float* st = style + b * 512;
    const float* wr = sw + c * 512;
    float a = 0.f;
#pragma unroll
    for (int j = 0; j < 8; ++j) a += st[lane + 64 * j] * wr[lane + 64 * j];
    for (int off = 32; off > 0; off >>= 1) a += __shfl_down(a, off, 64);
    if (lane == 0) s_out[gw] = a + sbias[c];
}

// sig_inv[b,o] = rsqrt( sum_i (sum_tap W[o,i,tap]^2) * s[b,i]^2 + 1e-8 )
__global__ void k_sig(const float* __restrict__ weight, const float* __restrict__ s,
                      float* __restrict__ sig) {
    int gw = (blockIdx.x * blockDim.x + threadIdx.x) >> 6;
    int lane = threadIdx.x & 63;
    if (gw >= 512) return;
    int b = gw >> 7, o = gw & 127;
    float a = 0.f;
#pragma unroll
    for (int j = 0; j < 2; ++j) {
        int i = lane + 64 * j;
        const float* wr = weight + ((size_t)o * 128 + i) * 9;
        float wsq = 0.f;
#pragma unroll
        for (int t = 0; t < 9; ++t) wsq += wr[t] * wr[t];
        float sv = s[b * 128 + i];
        a += wsq * sv * sv;
    }
    for (int off = 32; off > 0; off >>= 1) a += __shfl_down(a, off, 64);
    if (lane == 0) sig[gw] = rsqrtf(a + 1e-8f);
}

// repack + style-fold: fp32 W[co][ci][9] * s[b][ci] ->
// bf16 wt[b4][chunk8][tap9][g2][co128][8ci]
__global__ void k_wt(const float* __restrict__ weight, const float* __restrict__ s,
                     bf16* __restrict__ wt) {
    int i = blockIdx.x * 256 + threadIdx.x;
    if (i >= 589824) return;
    int j = i & 7;
    int co = (i >> 3) & 127;
    int g = (i >> 10) & 1;
    int tap = (i >> 11) % 9;
    int cb = (i >> 11) / 9;      // chunk + 8*b
    int chunk = cb & 7, b = cb >> 3;
    int ci = chunk * 16 + g * 8 + j;
    wt[i] = (bf16)(weight[((size_t)co * 128 + ci) * 9 + tap] * s[b * 128 + ci]);
}

// ---------------- main MFMA conv kernel ----------------
// grid 1024 (1-D, XCD-swizzled); block 256 = 4 waves; tile 128co x 256elem.
// Session-final structure (r11, measured best total 111.5us):
// 24-coarse-phase machine, style folded into per-batch wt (k_xt pass
// deleted), X read directly from fp32 x, T1 XCD swizzle (FETCH 165->75MB).
//   logical = (hw&7)*128 + (hw>>3)   (bijective, 1024 % 8 == 0)
// Per phase p (row = (chunk, dh) = p/3, p%3):
//   1. wslab(p+1): 3 global_load_lds DMAs (W ring slot (p+1)%3)
//   2. xstore(p): cvt XL regs (loaded p-1) -> bf16x8 -> 3 ds_write_b128
//   3. xload(p+1): 24 fp32 global loads into XL regs (1 phase of lead)
//   4. vmcnt(27); lgkmcnt(0); s_barrier
//   5. compute(p): 18 ds_read_b128 + 24 MFMA
// Ring safety: 3 slots, write at p overwrites p-3; barrier(p-1) collectively
// retires compute(p-2) and earlier. vmcnt ledger: steady 27; final drain 0.
// LDS: 3*9216(X) + 3*12288(W) = 64512 B -> 2 blocks/CU.
// NOTE (session evidence): setprio spills at the 128-VGPR cap (r10); A-from-
// global spills + stalls (r14); no-LDS dataflow slower (r12/r13); occupancy
// and sync-granularity changes null (r5-r8). Do not re-derive without new
// counter evidence.
__global__ __launch_bounds__(256, 2) void conv_main(
    const float* __restrict__ x, const bf16* __restrict__ wt,
    const float* __restrict__ sig_inv, const float* __restrict__ npar,
    const float* __restrict__ bpar, const float* __restrict__ noise,
    float* __restrict__ out) {
    __shared__ bf16 Xr[3][576 * 8];    // 3 x 9216 B  X row ring [g2][e288][8ci]
    __shared__ bf16 Wr[3][768 * 8];    // 3 x 12288 B W dh-slab ring [dw3][g2][co128][8ci]

    const int tid = threadIdx.x;
    const int lane = tid & 63;
    const int l31 = lane & 31, lhi = lane >> 5;
    const int wm = (tid >> 6) & 1;     // co half (64co)
    const int wn = tid >> 7;           // el half (128el)

    // T1 swizzle: hardware id -> logical work id (XCD gets contiguous chunk)
    const int hw = blockIdx.x;
    const int logical = (hw & 7) * 128 + (hw >> 3);
    const int w0 = (logical & 3) * 16;
    const int h = (logical >> 2) & 63;
    const int b = logical >> 8;

    const size_t bHW = (size_t)b * 65536;
    const bf16* wb = wt + (size_t)b * 147456;

    float XL[24];                      // in-flight X row (3 cells x 8 ci)

    // W dh-slab s (= 3*chunk + dh): 768 cells, exactly 3 DMAs per thread.
    auto wslab = [&](int s) {
        int slot = s % 3;
#pragma unroll
        for (int it = 0; it < 3; ++it) {
            int v = it * 256 + tid;
            async_copy16(wb + (size_t)s * 6144 + v * 8, &Wr[slot][v * 8]);
        }
    };

    // issue 24 fp32 loads for row g (3 cells/thread, wrap-dup past 576).
    auto xload = [&](int g) {
        int cg = g / 3, dhg = g - cg * 3;
        int ha = h - 1 + dhg;
#pragma unroll
        for (int cc = 0; cc < 3; ++cc) {
            int v0 = cc * 256 + tid;
            int v = v0 >= 576 ? v0 - 576 : v0;
            int gg = v / 288, e = v - gg * 288;
            int wa = w0 - 1 + (e >> 4);
            bool ok = ((unsigned)ha < 64u) & ((unsigned)wa < 64u);
            int E = (ha * 64 + wa) * 16 + (e & 15);
            int Ec = ok ? E : 0;       // clamp: loads always in-bounds
            const AS1 float* xp = (const AS1 float*)x +
                (((size_t)(b * 128 + cg * 16 + gg * 8)) << 16) + Ec;
#pragma unroll
            for (int j = 0; j < 8; ++j) XL[cc * 8 + j] = xp[(size_t)j << 16];
        }
    };

    // cvt + ds_write row g from XL (halo rows/cols zeroed by value-select).
    auto xstore = [&](int g) {
        int dhg = g % 3;
        int ha = h - 1 + dhg;
        const bf16 zz = (bf16)0.f;
        const bf16x8 vz = {zz, zz, zz, zz, zz, zz, zz, zz};
#pragma unroll
        for (int cc = 0; cc < 3; ++cc) {
            int v0 = cc * 256 + tid;
            int v = v0 >= 576 ? v0 - 576 : v0;
            int gg = v / 288, e = v - gg * 288;
            int wa = w0 - 1 + (e >> 4);
            bool ok = ((unsigned)ha < 64u) & ((unsigned)wa < 64u);
            bf16x8 vv;
#pragma unroll
            for (int j = 0; j < 8; ++j) vv[j] = (bf16)XL[cc * 8 + j];
            vv = ok ? vv : vz;
            *(bf16x8*)&Xr[dhg][v * 8] = vv;
        }
    };

    f32x16 acc[2][4] = {};

    // epilogue noise first: oldest in vmcnt, retired by the first store-wait
    const size_t ebase = bHW + (size_t)h * 1024 + w0 * 16 + wn * 128;
    float ns[4];
#pragma unroll
    for (int nf = 0; nf < 4; ++nf) ns[nf] = noise[ebase + nf * 32 + l31];
    __builtin_amdgcn_sched_barrier(0);

    // prologue: XL <- row 0, W slab 0
    xload(0);
    wslab(0);
    __builtin_amdgcn_sched_barrier(0);

#define PHASE(c, dh, LIT, DONEXT)                                              \
    {                                                                          \
        if (DONEXT) wslab(3 * (c) + (dh) + 1);                                 \
        xstore(3 * (c) + (dh));                                                \
        if (DONEXT) xload(3 * (c) + (dh) + 1);                                 \
        __builtin_amdgcn_sched_barrier(0);                                     \
        waitv<LIT>();                                                          \
        asm volatile("s_waitcnt lgkmcnt(0)" ::: "memory");                     \
        __builtin_amdgcn_sched_barrier(0);                                     \
        __builtin_amdgcn_s_barrier();                                          \
        _Pragma("unroll")                                                      \
        for (int dw = 0; dw < 3; ++dw) {                                       \
            const bf16* wg =                                                   \
                &Wr[dh][((dw * 2 + lhi) * 128 + wm * 64 + l31) * 8];           \
            bf16x8 a0 = *(const bf16x8*)&wg[0];                                \
            bf16x8 a1 = *(const bf16x8*)&wg[32 * 8];                           \
            const bf16* xb =                                                   \
                &Xr[dh][(lhi * 288 + dw * 16 + wn * 128 + l31) * 8];           \
            bf16x8 b0 = *(const bf16x8*)&xb[0];                                \
            bf16x8 b1 = *(const bf16x8*)&xb[32 * 8];                           \
            bf16x8 b2 = *(const bf16x8*)&xb[64 * 8];                           \
            bf16x8 b3 = *(const bf16x8*)&xb[96 * 8];                           \
            acc[0][0] = __builtin_amdgcn_mfma_f32_32x32x16_bf16(a0, b0, acc[0][0], 0, 0, 0); \
            acc[0][1] = __builtin_amdgcn_mfma_f32_32x32x16_bf16(a0, b1, acc[0][1], 0, 0, 0); \
            acc[0][2] = __builtin_amdgcn_mfma_f32_32x32x16_bf16(a0, b2, acc[0][2], 0, 0, 0); \
            acc[0][3] = __builtin_amdgcn_mfma_f32_32x32x16_bf16(a0, b3, acc[0][3], 0, 0, 0); \
            acc[1][0] = __builtin_amdgcn_mfma_f32_32x32x16_bf16(a1, b0, acc[1][0], 0, 0, 0); \
            acc[1][1] = __builtin_amdgcn_mfma_f32_32x32x16_bf16(a1, b1, acc[1][1], 0, 0, 0); \
            acc[1][2] = __builtin_amdgcn_mfma_f32_32x32x16_bf16(a1, b2, acc[1][2], 0, 0, 0); \
            acc[1][3] = __builtin_amdgcn_mfma_f32_32x32x16_bf16(a1, b3, acc[1][3], 0, 0, 0); \
        }                                                                      \
    }

    for (int c = 0; c < 7; ++c) {
        PHASE(c, 0, 27, true);
        PHASE(c, 1, 27, true);
        PHASE(c, 2, 27, true);
    }
    PHASE(7, 0, 27, true);
    PHASE(7, 1, 27, true);    // p=22: issues W23 + XL23
    PHASE(7, 2, 0, false);    // p=23: store row 23, drain, compute
#undef PHASE

    // epilogue: D col = lane&31 (elem), row = (reg&3)+8*(reg>>2)+4*lhi (co)
#pragma unroll
    for (int fm = 0; fm < 2; ++fm) {
        int cob = wm * 64 + fm * 32 + 4 * lhi;
#pragma unroll
        for (int q = 0; q < 4; ++q) {
            int co4 = cob + 8 * q;
            f32x4 sg = *(const f32x4*)&sig_inv[b * 128 + co4];
            f32x4 np4 = *(const f32x4*)&npar[co4];
            f32x4 bp4 = *(const f32x4*)&bpar[co4];
#pragma unroll
            for (int r = 0; r < 4; ++r) {
                int co = co4 + r;
                float* orow = out + ((size_t)(b * 128 + co) * 64 + h) * 1024 +
                              w0 * 16 + wn * 128;
#pragma unroll
                for (int nf = 0; nf < 4; ++nf) {
                    float v = acc[fm][nf][q * 4 + r];
                    orow[nf * 32 + l31] = v * sg[r] + np4[r] * ns[nf] + bp4[r];
                }
            }
        }
    }
}

// ---------------- fp32 fallback (ws too small) ----------------
__global__ void k_naive(const float* __restrict__ x, const float* __restrict__ weight,
                        const float* __restrict__ s, const float* __restrict__ sig,
                        const float* __restrict__ npar, const float* __restrict__ bpar,
                        const float* __restrict__ noise, float* __restrict__ out) {
    size_t o = (size_t)blockIdx.x * 256 + threadIdx.x;
    int t = o & 15, w = (o >> 4) & 63, h = (o >> 10) & 63;
    int co = (o >> 16) & 127, b = (int)(o >> 23);
    float a = 0.f;
    for (int ci = 0; ci < 128; ++ci) {
        const float* xr = x + (size_t)(b * 128 + ci) * 65536;
        const float* wr = weight + ((size_t)co * 128 + ci) * 9;
        float p = 0.f;
#pragma unroll
        for (int kh = 0; kh < 3; ++kh) {
            int ha = h + kh - 1;
            if ((unsigned)ha >= 64u) continue;
#pragma unroll
            for (int kw = 0; kw < 3; ++kw) {
                int wa = w + kw - 1;
                if ((unsigned)wa >= 64u) continue;
                p += xr[(ha * 64 + wa) * 16 + t] * wr[kh * 3 + kw];
            }
        }
        a += p * s[b * 128 + ci];
    }
    int E = b * 65536 + (h * 64 + w) * 16 + t;
    out[o] = a * sig[b * 128 + co] + npar[co] * noise[E] + bpar[co];
}

// ---------------- host ----------------
extern "C" void kernel_launch(void* const* d_in, const int* in_sizes, int n_in,
                              void* d_out, int out_size, void* d_ws, size_t ws_size,
                              hipStream_t stream) {
    const float* x      = (const float*)d_in[0];
    const float* style  = (const float*)d_in[1];
    const float* noise  = (const float*)d_in[2];
    const float* weight = (const float*)d_in[3];
    const float* sw     = (const float*)d_in[4];
    const float* sb     = (const float*)d_in[5];
    const float* npar   = (const float*)d_in[6];
    const float* bpar   = (const float*)d_in[7];
    float* out = (float*)d_out;

    float* s_buf   = (float*)d_ws;                         // 512 f32
    float* sig_buf = s_buf + 512;                          // 512 f32
    bf16*  wt      = (bf16*)((char*)d_ws + 8192);          // 4 x 294912 B
    const size_t NEED = 8192 + 4 * 294912ull;

    k_style<<<dim3(128), dim3(256), 0, stream>>>(style, sw, sb, s_buf);
    k_sig<<<dim3(128), dim3(256), 0, stream>>>(weight, s_buf, sig_buf);
    if (ws_size >= NEED) {
        k_wt<<<dim3(2304), dim3(256), 0, stream>>>(weight, s_buf, wt);
        conv_main<<<dim3(1024), dim3(256), 0, stream>>>(
            x, wt, sig_buf, npar, bpar, noise, out);
    } else {
        k_naive<<<dim3(131072), dim3(256), 0, stream>>>(
            x, weight, s_buf, sig_buf, npar, bpar, noise, out);
    }
}